// Round 5
// baseline (493.603 us; speedup 1.0000x reference)
//
#include <hip/hip_runtime.h>
#include <stdint.h>

#define BB 1024
#define SS 512
#define HH 128
#define MM 2            // batch rows per block
#define BLK 512         // 8 waves; 2 blocks/CU -> 4 waves/SIMD, independent barriers
#define NBLK (BB / MM)  // 512 blocks -> 2 per CU
#define RS 32           // h-trajectory ring slots (flush every 32 steps)
#define RStr 136        // ring row stride in f16

typedef float f32x4 __attribute__((ext_vector_type(4)));
typedef float f32x2 __attribute__((ext_vector_type(2)));
typedef _Float16 f16x8 __attribute__((ext_vector_type(8)));

#define LO_SCALE 2048.0f
#define LO_INV   (1.0f / 2048.0f)
#define L2E      1.44269504088896f

__device__ __forceinline__ float rcp_fast(float x)  { return __builtin_amdgcn_rcpf(x); }
__device__ __forceinline__ float exp2_fast(float x) { return __builtin_amdgcn_exp2f(x); }
// lane <- lane^1, pure-VALU DPP (quad_perm [1,0,3,2] = 0xB1) — NOT ds_swizzle
__device__ __forceinline__ unsigned int dpp_xor1(unsigned int x) {
    return (unsigned int)__builtin_amdgcn_update_dpp(0, (int)x, 0xB1, 0xF, 0xF, true);
}

__global__ __launch_bounds__(BLK, 4) void pig_kernel(
    const float* __restrict__ x0, const float* __restrict__ v_seq,
    const float* __restrict__ W_ih, const float* __restrict__ W_hh,
    const float* __restrict__ b_ih, const float* __restrict__ b_hh,
    const float* __restrict__ W_out, const float* __restrict__ b_out,
    const float* __restrict__ W_r1, const float* __restrict__ b_r1,
    const float* __restrict__ W_r2, const float* __restrict__ b_r2,
    float* __restrict__ out)
{
    // hp2: [parity][kk 0..3][q 0..3][rr 0..3][8 f16] = 512 f16/parity (1 KB).
    // rr = 2m+p (m 0..1; p: 0=hi, 1=lo*2048).  A rows are 4x-replicated
    // (row' = col&3), so acc regs [0..3] of EVERY lane = gh for
    // [m0 hi, m0 lo, m1 hi, m1 lo] at j=its col.  Lane's own batch row mq=quad&1
    // picked via compile-time extracts; quads 2,3 compute duplicates and skip
    // the writes.  Writes b32 pair-packed via DPP (no same-word b16 collisions).
    __shared__ __align__(16) _Float16 hp2[2][512];          // 2 KB
    __shared__ __align__(16) _Float16 ring[RS * 2 * RStr];  // 17 KB: [slot][m][j]
    __shared__ __align__(16) float    v_lds[SS * 4];        // 8 KB: [t][m*2+o]
    __shared__ __align__(16) float    xs[RS + 1][4];        // x_pred window (+carry at [0])
    __shared__ __align__(16) float    wpk[64][8];           // {W_r1[u][0..3], b_r1[u], W_r2[0][u], W_r2[1][u], 0}
    __shared__ float xc[2][4];                              // x_prev carry, flush-parity buffered

    const int tid  = threadIdx.x;
    const int wave = tid >> 6;          // 0..7
    const int lane = tid & 63;
    const int quad = lane >> 4;
    const int col  = lane & 15;
    const int row0 = blockIdx.x * MM;
    const int mq   = quad & 1;          // this lane's batch row (quads 2,3 duplicate)
    const int j    = wave * 16 + col;   // this lane's hidden index

    // ---- W_hh B-fragments (f16): wave w owns gates nt*128 + w*16 .. +15 ----
    f16x8 whi[3][4];
#pragma unroll
    for (int nt = 0; nt < 3; ++nt) {
        const int g = nt * HH + j;
#pragma unroll
        for (int kk = 0; kk < 4; ++kk) {
            const float* p = W_hh + g * HH + kk * 32 + quad * 8;
            f16x8 fh;
#pragma unroll
            for (int i = 0; i < 8; ++i) fh[i] = (_Float16)p[i];
            whi[nt][kk] = fh;
        }
    }

    // ---- gate-math per-lane constants (hidden index j, batch row mq) ----
    const float wr0 = W_ih[j*2],        wr1 = W_ih[j*2+1];
    const float wz0 = W_ih[(HH+j)*2],   wz1 = W_ih[(HH+j)*2+1];
    const float wn0 = W_ih[(2*HH+j)*2], wn1 = W_ih[(2*HH+j)*2+1];
    const float br  = b_ih[j]      + b_hh[j];
    const float bz  = b_ih[HH+j]   + b_hh[HH+j];
    const float bni = b_ih[2*HH+j];
    const float bnh = b_hh[2*HH+j];

    // ---- hp2 addressing ----
    const int rbase = quad * 32 + (col & 3) * 8;    // read (+kk*128 f16)
    // write (b32 pair, even cols of quads 0,1): hi word; lo at +8
    const int wbase = (j >> 5) * 128 + ((j >> 3) & 3) * 32 + 2 * mq * 8 + (j & 7);

    // ---- pass-A constants: g8 = tid>>3 -> (o, m, tt8); lane-in-group l8 ----
    const int g8  = tid >> 3;           // 0..63
    const int l8  = tid & 7;
    const int oA  = g8 & 1;
    const int mA  = (g8 >> 1) & 1;
    const int tt8 = g8 >> 2;            // 0..15
    float woA[16];
#pragma unroll
    for (int i = 0; i < 16; ++i) woA[i] = W_out[oA * HH + l8 * 16 + i];
    const float boA = b_out[oA];

    // ---- pass-B constants: (tB, mB, qB), threads 0..255 ----
    const int qB = tid & 3;
    const int mB = (tid >> 2) & 1;
    const int tB = (tid >> 3) & 31;
    const float b2B = b_r2[qB & 1];

    // ---- init ----
    for (int idx = tid; idx < 2 * 512; idx += BLK) ((_Float16*)hp2)[idx] = (_Float16)0.0f;
    for (int idx = tid; idx < MM * SS * 2; idx += BLK) {
        const int m = idx >> 10, i = idx & 1023;          // i = t*2 + o
        v_lds[(i >> 1) * 4 + m * 2 + (i & 1)] = v_seq[(size_t)(row0 + m) * (SS * 2) + i];
    }
    if (tid < 64) {   // packed residual-MLP weights
        wpk[tid][0] = W_r1[tid*4];   wpk[tid][1] = W_r1[tid*4+1];
        wpk[tid][2] = W_r1[tid*4+2]; wpk[tid][3] = W_r1[tid*4+3];
        wpk[tid][4] = b_r1[tid];
        wpk[tid][5] = W_r2[tid];     wpk[tid][6] = W_r2[64 + tid];
        wpk[tid][7] = 0.0f;
    }
    if (tid < 4)
        xc[0][tid] = x0[(size_t)(row0 + (tid >> 1)) * 2 + (tid & 1)];
    __syncthreads();

    float hold = 0.0f;   // h[mq][j] in fp32 — the only recurrent state
    f32x2 vv2 = *(const f32x2*)&v_lds[mq * 2];
    // x-projection terms hoisted off the post-MFMA critical path
    float vxr = vv2[0]*wr0 + vv2[1]*wr1 + br;
    float vxz = vv2[0]*wz0 + vv2[1]*wz1 + bz;
    float vxn = vv2[0]*wn0 + vv2[1]*wn1 + bni;

    for (int t = 0; t < SS; ++t) {
        const int cur = t & 1, nxt = cur ^ 1;

        // ---------- recurrence: 12 MFMA ----------
        f32x4 aH0 = {0,0,0,0}, aH1 = {0,0,0,0}, aH2 = {0,0,0,0};
        const _Float16* hb = &hp2[cur][rbase];
#pragma unroll
        for (int kk = 0; kk < 4; ++kk) {
            f16x8 af = *(const f16x8*)&hb[kk * 128];
            aH0 = __builtin_amdgcn_mfma_f32_16x16x32_f16(af, whi[0][kk], aH0, 0, 0, 0);
            aH1 = __builtin_amdgcn_mfma_f32_16x16x32_f16(af, whi[1][kk], aH1, 0, 0, 0);
            aH2 = __builtin_amdgcn_mfma_f32_16x16x32_f16(af, whi[2][kk], aH2, 0, 0, 0);
        }
        // acc regs [0..3] = [m0 hi, m0 lo, m1 hi, m1 lo]; compile-time extracts
        const float gh0 = fmaf(mq ? aH0[3] : aH0[1], LO_INV, mq ? aH0[2] : aH0[0]);
        const float gh1 = fmaf(mq ? aH1[3] : aH1[1], LO_INV, mq ? aH1[2] : aH1[0]);
        const float gh2 = fmaf(mq ? aH2[3] : aH2[1], LO_INV, mq ? aH2[2] : aH2[0]);

        const float r  = rcp_fast(1.0f + exp2_fast((gh0 + vxr) * (-L2E)));
        const float z  = rcp_fast(1.0f + exp2_fast((gh1 + vxz) * (-L2E)));
        const float na = vxn + r * (gh2 + bnh);
        const float n  = fmaf(2.0f, rcp_fast(1.0f + exp2_fast(na * (-2.0f * L2E))), -1.0f);
        hold = fmaf(z, hold - n, n);

        // ---------- DPP-packed b32 writes (16 lanes/wave) ----------
        const _Float16 hh = (_Float16)hold;
        const _Float16 hl = (_Float16)((hold - (float)hh) * LO_SCALE);
        const unsigned int uh = (unsigned int)__builtin_bit_cast(unsigned short, hh);
        const unsigned int ul = (unsigned int)__builtin_bit_cast(unsigned short, hl);
        const unsigned int ph = uh | (dpp_xor1(uh) << 16);   // (h_j, h_j+1) on even cols
        const unsigned int pl = ul | (dpp_xor1(ul) << 16);
        if (quad < 2 && !(col & 1)) {
            *(unsigned int*)&hp2[nxt][wbase]     = ph;
            *(unsigned int*)&hp2[nxt][wbase + 8] = pl;
            *(unsigned int*)&ring[((t & (RS-1)) * 2 + mq) * RStr + j] = ph;
        }

        // prefetch + precompute next step's x-projection (runs in barrier shadow)
        vv2 = *(const f32x2*)&v_lds[((t + 1) & (SS - 1)) * 4 + mq * 2];
        vxr = vv2[0]*wr0 + vv2[1]*wr1 + br;
        vxz = vv2[0]*wz0 + vv2[1]*wz1 + bz;
        vxn = vv2[0]*wn0 + vv2[1]*wn1 + bni;

        __syncthreads();

        // ---------- batched epilogue every RS steps ----------
        if ((t & (RS - 1)) == (RS - 1)) {
            const int f  = t >> 5;       // flush index
            const int t0 = t - (RS - 1);

            // pass A: x_pred for the window (8-lane dot groups, 2 passes)
            if (tid < 4) xs[0][tid] = xc[f & 1][tid];
#pragma unroll
            for (int p = 0; p < 2; ++p) {
                const int tt = p * 16 + tt8;
                const f16x8 h0 = *(const f16x8*)&ring[(tt * 2 + mA) * RStr + l8 * 16];
                const f16x8 h1 = *(const f16x8*)&ring[(tt * 2 + mA) * RStr + l8 * 16 + 8];
                float acc = 0.0f;
#pragma unroll
                for (int i = 0; i < 8; ++i) {
                    acc += (float)h0[i] * woA[i];
                    acc += (float)h1[i] * woA[8 + i];
                }
                acc += __shfl_xor(acc, 1, 64);
                acc += __shfl_xor(acc, 2, 64);
                acc += __shfl_xor(acc, 4, 64);
                if (l8 == 0) xs[1 + tt][mA * 2 + oA] = acc + boA;
            }
            __syncthreads();

            // pass B: residual MLP + violations + stores; threads 0..255
            if (tid < 256) {
                const float xp0 = xs[tB][mB*2], xp1 = xs[tB][mB*2+1];
                const f32x2 vt2 = *(const f32x2*)&v_lds[(t0 + tB) * 4 + mB * 2];
                float rss0 = 0.0f, rss1 = 0.0f;
#pragma unroll
                for (int uu = 0; uu < 16; ++uu) {
                    const int u = qB * 16 + uu;
                    const f32x4 wA = *(const f32x4*)&wpk[u][0];
                    const f32x4 wB = *(const f32x4*)&wpk[u][4];
                    const float hu = fmaxf(wB[0] + wA[0]*xp0 + wA[1]*xp1 + wA[2]*vt2[0] + wA[3]*vt2[1], 0.0f);
                    rss0 += hu * wB[1];
                    rss1 += hu * wB[2];
                }
                rss0 += __shfl_xor(rss0, 1, 64);
                rss1 += __shfl_xor(rss1, 1, 64);
                rss0 += __shfl_xor(rss0, 2, 64);
                rss1 += __shfl_xor(rss1, 2, 64);
                if (qB < 2) {
                    const int o = qB;
                    const float xpred = xs[tB + 1][mB*2 + o];
                    const float xpv   = xs[tB][mB*2 + o];
                    const float vv    = v_lds[(t0 + tB) * 4 + mB*2 + o];
                    const float resid = (o ? rss1 : rss0) + b2B;
                    const float viol  = xpred - (xpv + vv + resid);
                    const size_t base = (size_t)(row0 + mB) * (SS * 2) + (t0 + tB) * 2 + o;
                    out[base] = xpred;
                    out[(size_t)BB * SS * 2 + base] = viol;
                }
                if (tid < 4) xc[(f + 1) & 1][tid] = xs[RS][tid];   // carry to next window
            }
            __syncthreads();
        }
    }
}

extern "C" void kernel_launch(void* const* d_in, const int* in_sizes, int n_in,
                              void* d_out, int out_size, void* d_ws, size_t ws_size,
                              hipStream_t stream) {
    pig_kernel<<<dim3(NBLK), dim3(BLK), 0, stream>>>(
        (const float*)d_in[0],  (const float*)d_in[1],  (const float*)d_in[2],
        (const float*)d_in[3],  (const float*)d_in[4],  (const float*)d_in[5],
        (const float*)d_in[6],  (const float*)d_in[7],  (const float*)d_in[8],
        (const float*)d_in[9],  (const float*)d_in[10], (const float*)d_in[11],
        (float*)d_out);
}

// Round 7
// 362.722 us; speedup vs baseline: 1.3608x; 1.3608x over previous
//
#include <hip/hip_runtime.h>
#include <stdint.h>

#define BB 1024
#define SS 512
#define HH 128
#define MM 4            // batch rows per block
#define BLK 512         // 8 waves, 1 block/CU, 2 waves/SIMD
#define NBLK (BB / MM)  // 256 blocks -> 1 per CU
#define RS 32           // x_pred window (flush every 32 steps)

typedef float f32x4 __attribute__((ext_vector_type(4)));
typedef float f32x2 __attribute__((ext_vector_type(2)));
typedef _Float16 f16x8 __attribute__((ext_vector_type(8)));

#define LO_SCALE 2048.0f
#define LO_INV   (1.0f / 2048.0f)
#define L2E      1.44269504088896f

__device__ __forceinline__ float rcp_fast(float x)  { return __builtin_amdgcn_rcpf(x); }
__device__ __forceinline__ float exp2_fast(float x) { return __builtin_amdgcn_exp2f(x); }

__global__ __launch_bounds__(BLK, 2) void pig_kernel(
    const float* __restrict__ x0, const float* __restrict__ v_seq,
    const float* __restrict__ W_ih, const float* __restrict__ W_hh,
    const float* __restrict__ b_ih, const float* __restrict__ b_hh,
    const float* __restrict__ W_out, const float* __restrict__ b_out,
    const float* __restrict__ W_r1, const float* __restrict__ b_r1,
    const float* __restrict__ W_r2, const float* __restrict__ b_r2,
    float* __restrict__ out)
{
    // hp2: [parity][kk 0..3][quadk 0..3][row' 0..7][8 f16] = 2 KB/parity.
    // row' = 2m+p (p: 0=hi, 1=lo*2048).  MFMA A rows mirror via rr(col); acc
    // regs [0],[1] of lane(quad,col) = (hi,lo) dots for m=quad.
    // x_pred comes from a 4th MFMA tile (B = W_out) on the SAME A-fragments.
    // Phase fix vs R6: iteration t's A = h[t-1], so the x-tile yields xp[t-1];
    // slots are written for t-1 and the flush fires at (t&31)==0 (window
    // [t-32, t-1] complete); xp[511] is produced by a 4-MFMA epilogue.
    __shared__ __align__(16) _Float16 hp2[2][1024];   // 4 KB
    __shared__ __align__(16) float    v_lds[SS * 8];  // 16 KB: [t][m*2+o]
    __shared__ __align__(16) float    xs[RS + 1][8];  // x_pred window; xs[0] = carry
    __shared__ __align__(16) float    wpk[64][8];     // {W_r1[u][0..3], b_r1[u], W_r2[0][u], W_r2[1][u], 0}

    const int tid  = threadIdx.x;
    const int wave = tid >> 6;
    const int lane = tid & 63;
    const int quad = lane >> 4;         // batch row m for this lane
    const int col  = lane & 15;
    const int row0 = blockIdx.x * MM;
    const int j    = wave * 16 + col;   // this lane's hidden index

    // ---- W_hh B-fragments (f16): wave w owns gates nt*128 + w*16 .. +15 ----
    f16x8 whi[3][4];
#pragma unroll
    for (int nt = 0; nt < 3; ++nt) {
        const int g = nt * HH + j;
#pragma unroll
        for (int kk = 0; kk < 4; ++kk) {
            const float* p = W_hh + g * HH + kk * 32 + quad * 8;
            f16x8 fh;
#pragma unroll
            for (int i = 0; i < 8; ++i) fh[i] = (_Float16)p[i];
            whi[nt][kk] = fh;
        }
    }

    // ---- x-tile B-fragment: n-col o = col&1 (cols 2..15 duplicate, unused) ----
    f16x8 wxo[4];
    const int oX = col & 1;
#pragma unroll
    for (int kk = 0; kk < 4; ++kk) {
        const float* p = W_out + oX * HH + kk * 32 + quad * 8;
        f16x8 fh;
#pragma unroll
        for (int i = 0; i < 8; ++i) fh[i] = (_Float16)p[i];
        wxo[kk] = fh;
    }
    const float boX = b_out[oX];

    // ---- gate-math per-lane constants (hidden index j, batch row m=quad) ----
    const float wr0 = W_ih[j*2],        wr1 = W_ih[j*2+1];
    const float wz0 = W_ih[(HH+j)*2],   wz1 = W_ih[(HH+j)*2+1];
    const float wn0 = W_ih[(2*HH+j)*2], wn1 = W_ih[(2*HH+j)*2+1];
    const float br  = b_ih[j]      + b_hh[j];
    const float bz  = b_ih[HH+j]   + b_hh[HH+j];
    const float bni = b_ih[2*HH+j];
    const float bnh = b_hh[2*HH+j];

    // ---- hp2 addressing ----
    const int rr    = ((col >> 2) << 1) | (col & 1);   // row' read map (col&2 mirrors)
    const int rbase = quad * 64 + rr * 8;              // f16 units (+kk*256)
    const int wbase = (j >> 5) * 256 + ((j >> 3) & 3) * 64 + quad * 16 + (j & 7);

    // ---- pass-B constants: (tB, mB, qB) ----
    const int qB = tid & 3;
    const int mB = (tid >> 2) & 3;
    const int tB = tid >> 4;            // 0..31
    const float b2B = b_r2[qB & 1];

    // ---- init ----
    for (int idx = tid; idx < 2 * 1024; idx += BLK) ((_Float16*)hp2)[idx] = (_Float16)0.0f;
    for (int idx = tid; idx < MM * SS * 2; idx += BLK) {
        const int m = idx >> 10, i = idx & 1023;          // i = t*2 + o
        v_lds[(i >> 1) * 8 + m * 2 + (i & 1)] = v_seq[(size_t)(row0 + m) * (SS * 2) + i];
    }
    if (tid < 64) {   // packed residual-MLP weights
        wpk[tid][0] = W_r1[tid*4];   wpk[tid][1] = W_r1[tid*4+1];
        wpk[tid][2] = W_r1[tid*4+2]; wpk[tid][3] = W_r1[tid*4+3];
        wpk[tid][4] = b_r1[tid];
        wpk[tid][5] = W_r2[tid];     wpk[tid][6] = W_r2[64 + tid];
        wpk[tid][7] = 0.0f;
    }
    if (tid < 8)
        xs[0][tid] = x0[(size_t)(row0 + (tid >> 1)) * 2 + (tid & 1)];
    __syncthreads();

    // residual-MLP flush for window [t0, t0+31]; call with all 512 threads
    auto flush = [&](int t0) {
        const float xp0 = xs[tB][mB*2], xp1 = xs[tB][mB*2+1];
        const f32x2 vt2 = *(const f32x2*)&v_lds[(t0 + tB) * 8 + mB * 2];
        float rss0 = 0.0f, rss1 = 0.0f;
#pragma unroll
        for (int uu = 0; uu < 16; ++uu) {
            const int u = qB * 16 + uu;
            const f32x4 wA = *(const f32x4*)&wpk[u][0];
            const f32x4 wB = *(const f32x4*)&wpk[u][4];
            const float hu = fmaxf(wB[0] + wA[0]*xp0 + wA[1]*xp1 + wA[2]*vt2[0] + wA[3]*vt2[1], 0.0f);
            rss0 += hu * wB[1];
            rss1 += hu * wB[2];
        }
        rss0 += __shfl_xor(rss0, 1, 64);
        rss1 += __shfl_xor(rss1, 1, 64);
        rss0 += __shfl_xor(rss0, 2, 64);
        rss1 += __shfl_xor(rss1, 2, 64);
        if (qB < 2) {
            const int o = qB;
            const float xpred = xs[tB + 1][mB*2 + o];
            const float xpv   = xs[tB][mB*2 + o];
            const float vv    = v_lds[(t0 + tB) * 8 + mB*2 + o];
            const float resid = (o ? rss1 : rss0) + b2B;
            const float viol  = xpred - (xpv + vv + resid);
            const size_t base = (size_t)(row0 + mB) * (SS * 2) + (t0 + tB) * 2 + o;
            out[base] = xpred;
            out[(size_t)BB * SS * 2 + base] = viol;
        }
    };

    float hold = 0.0f;   // h[quad][j] in fp32 — the only recurrent state
    f32x2 vv2 = *(const f32x2*)&v_lds[quad * 2];
    // x-projection terms hoisted off the post-MFMA critical path
    float vxr = vv2[0]*wr0 + vv2[1]*wr1 + br;
    float vxz = vv2[0]*wz0 + vv2[1]*wz1 + bz;
    float vxn = vv2[0]*wn0 + vv2[1]*wn1 + bni;

    for (int t = 0; t < SS; ++t) {
        const int cur = t & 1, nxt = cur ^ 1;

        // ---------- recurrence: 12 gate MFMA + 4 x-tile MFMA (A = h[t-1]) ----------
        f32x4 aH0 = {0,0,0,0}, aH1 = {0,0,0,0}, aH2 = {0,0,0,0}, aX = {0,0,0,0};
        const _Float16* hb = &hp2[cur][rbase];
#pragma unroll
        for (int kk = 0; kk < 4; ++kk) {
            f16x8 af = *(const f16x8*)&hb[kk * 256];
            aH0 = __builtin_amdgcn_mfma_f32_16x16x32_f16(af, whi[0][kk], aH0, 0, 0, 0);
            aH1 = __builtin_amdgcn_mfma_f32_16x16x32_f16(af, whi[1][kk], aH1, 0, 0, 0);
            aH2 = __builtin_amdgcn_mfma_f32_16x16x32_f16(af, whi[2][kk], aH2, 0, 0, 0);
            aX  = __builtin_amdgcn_mfma_f32_16x16x32_f16(af, wxo[kk],    aX,  0, 0, 0);
        }
        // acc[0] = h_hi . W ; acc[1] = (h_lo*2048) . W  -> exact-h gh
        const float gh0 = fmaf(aH0[1], LO_INV, aH0[0]);
        const float gh1 = fmaf(aH1[1], LO_INV, aH1[0]);
        const float gh2 = fmaf(aH2[1], LO_INV, aH2[0]);

        const float r  = rcp_fast(1.0f + exp2_fast((gh0 + vxr) * (-L2E)));
        const float z  = rcp_fast(1.0f + exp2_fast((gh1 + vxz) * (-L2E)));
        const float na = vxn + r * (gh2 + bnh);
        const float n  = fmaf(2.0f, rcp_fast(1.0f + exp2_fast(na * (-2.0f * L2E))), -1.0f);
        hold = fmaf(z, hold - n, n);

        const _Float16 hh = (_Float16)hold;
        hp2[nxt][wbase]     = hh;
        hp2[nxt][wbase + 8] = (_Float16)((hold - (float)hh) * LO_SCALE);

        // xp[t-1] from the x-tile (wave 0, lanes quad 0..3 x col 0..1)
        if (t && tid < 64 && col < 2)
            xs[1 + ((t - 1) & (RS - 1))][quad * 2 + col] = fmaf(aX[1], LO_INV, aX[0]) + boX;

        // prefetch + precompute next step's x-projection (barrier shadow)
        vv2 = *(const f32x2*)&v_lds[((t + 1) & (SS - 1)) * 8 + quad * 2];
        vxr = vv2[0]*wr0 + vv2[1]*wr1 + br;
        vxz = vv2[0]*wz0 + vv2[1]*wz1 + bz;
        vxn = vv2[0]*wn0 + vv2[1]*wn1 + bni;

        __syncthreads();

        // ---------- flush when window [t-32, t-1] is complete ----------
        if (t && (t & (RS - 1)) == 0) {
            flush(t - RS);
            __syncthreads();
            if (tid < 8) xs[0][tid] = xs[RS][tid];   // carry: xp[t-1] -> window head
        }
    }

    // ---------- epilogue: xp[511] from h[511] (parity 0), then final flush ----------
    {
        f32x4 aX = {0,0,0,0};
        const _Float16* hb = &hp2[0][rbase];
#pragma unroll
        for (int kk = 0; kk < 4; ++kk) {
            f16x8 af = *(const f16x8*)&hb[kk * 256];
            aX = __builtin_amdgcn_mfma_f32_16x16x32_f16(af, wxo[kk], aX, 0, 0, 0);
        }
        if (tid < 64 && col < 2)
            xs[RS][quad * 2 + col] = fmaf(aX[1], LO_INV, aX[0]) + boX;
        __syncthreads();
        flush(SS - RS);
    }
}

extern "C" void kernel_launch(void* const* d_in, const int* in_sizes, int n_in,
                              void* d_out, int out_size, void* d_ws, size_t ws_size,
                              hipStream_t stream) {
    pig_kernel<<<dim3(NBLK), dim3(BLK), 0, stream>>>(
        (const float*)d_in[0],  (const float*)d_in[1],  (const float*)d_in[2],
        (const float*)d_in[3],  (const float*)d_in[4],  (const float*)d_in[5],
        (const float*)d_in[6],  (const float*)d_in[7],  (const float*)d_in[8],
        (const float*)d_in[9],  (const float*)d_in[10], (const float*)d_in[11],
        (float*)d_out);
}

// Round 9
// 332.282 us; speedup vs baseline: 1.4855x; 1.0916x over previous
//
#include <hip/hip_runtime.h>
#include <stdint.h>

#define BB 1024
#define SS 512
#define HH 128
#define MM 4            // batch rows per block
#define BLK 512         // 8 waves, 1 block/CU, 2 waves/SIMD
#define NBLK (BB / MM)  // 256 blocks -> 1 per CU
#define RS 32           // h-trajectory ring slots (flush every 32 steps)
#define RStr 136        // ring row stride in f16

typedef float f32x4 __attribute__((ext_vector_type(4)));
typedef float f32x2 __attribute__((ext_vector_type(2)));
typedef _Float16 f16x8 __attribute__((ext_vector_type(8)));

#define LO_SCALE 2048.0f
#define LO_INV   (1.0f / 2048.0f)
#define L2E      1.44269504088896f

__device__ __forceinline__ float rcp_fast(float x)  { return __builtin_amdgcn_rcpf(x); }
__device__ __forceinline__ float exp2_fast(float x) { return __builtin_amdgcn_exp2f(x); }

__global__ __launch_bounds__(BLK, 2) void pig_kernel(
    const float* __restrict__ x0, const float* __restrict__ v_seq,
    const float* __restrict__ W_ih, const float* __restrict__ W_hh,
    const float* __restrict__ b_ih, const float* __restrict__ b_hh,
    const float* __restrict__ W_out, const float* __restrict__ b_out,
    const float* __restrict__ W_r1, const float* __restrict__ b_r1,
    const float* __restrict__ W_r2, const float* __restrict__ b_r2,
    float* __restrict__ out)
{
    // hp2: [parity][kk 0..3][quadk 0..3][row' 0..7][8 f16] = 2 KB/parity.
    // row' = 2m+p (p: 0=hi, 1=lo*2048).  A rows mirror via rr(col); lane
    // (quad,col) acc regs [0],[1] = (hi,lo) dots for m=quad at n-col=col.
    // Bank check (A-read): per quad the 8 unique b128 reads cover all 32 banks
    // with exactly 4 words/bank -> minimum service, no excess conflict.
    // MFMA chains split K-low/K-high: 6 independent 2-deep chains per wave
    // (vs 3x4-deep) to pull the MFMA pipe from latency rate toward throughput.
    __shared__ __align__(16) _Float16 hp2[2][1024];         // 4 KB
    __shared__ __align__(16) _Float16 ring[RS * 4 * RStr];  // 34 KB: [slot][m][j]
    __shared__ __align__(16) float    v_lds[SS * 8];        // 16 KB: [t][m*2+o]
    __shared__ __align__(16) float    xs[RS + 1][8];        // x_pred window (+carry at [0])
    __shared__ __align__(16) float    wpk[64][8];           // {W_r1[u][0..3], b_r1[u], W_r2[0][u], W_r2[1][u], 0}
    __shared__ float xc[2][8];                              // x_prev carry, flush-parity buffered

    const int tid  = threadIdx.x;
    const int wave = tid >> 6;
    const int lane = tid & 63;
    const int quad = lane >> 4;
    const int col  = lane & 15;
    const int row0 = blockIdx.x * MM;
    const int j    = wave * 16 + col;   // this lane's hidden index

    // ---- W_hh B-fragments (f16): wave w owns gates nt*128 + w*16 .. +15 ----
    f16x8 whi[3][4];
#pragma unroll
    for (int nt = 0; nt < 3; ++nt) {
        const int g = nt * HH + j;
#pragma unroll
        for (int kk = 0; kk < 4; ++kk) {
            const float* p = W_hh + g * HH + kk * 32 + quad * 8;
            f16x8 fh;
#pragma unroll
            for (int i = 0; i < 8; ++i) fh[i] = (_Float16)p[i];
            whi[nt][kk] = fh;
        }
    }

    // ---- gate-math per-lane constants (hidden index j, batch row m=quad) ----
    const float wr0 = W_ih[j*2],        wr1 = W_ih[j*2+1];
    const float wz0 = W_ih[(HH+j)*2],   wz1 = W_ih[(HH+j)*2+1];
    const float wn0 = W_ih[(2*HH+j)*2], wn1 = W_ih[(2*HH+j)*2+1];
    const float br  = b_ih[j]      + b_hh[j];
    const float bz  = b_ih[HH+j]   + b_hh[HH+j];
    const float bni = b_ih[2*HH+j];
    const float bnh = b_hh[2*HH+j];

    // ---- hp2 addressing ----
    const int rr    = ((col >> 2) << 1) | (col & 1);   // row' read map (col&2 mirrors)
    const int rbase = quad * 64 + rr * 8;              // f16 units (+kk*256)
    const int wbase = (j >> 5) * 256 + ((j >> 3) & 3) * 64 + quad * 16 + (j & 7);

    // ---- pass-A constants: group g8 = tid>>3 -> (o, m, tt8); lane-in-group l8 ----
    const int g8  = tid >> 3;
    const int l8  = tid & 7;
    const int oA  = g8 & 1;
    const int mA  = (g8 >> 1) & 3;
    const int tt8 = g8 >> 3;            // 0..7
    float woA[16];
#pragma unroll
    for (int i = 0; i < 16; ++i) woA[i] = W_out[oA * HH + l8 * 16 + i];
    const float boA = b_out[oA];

    // ---- pass-B constants: (tB, mB, qB) ----
    const int qB = tid & 3;
    const int mB = (tid >> 2) & 3;
    const int tB = tid >> 4;            // 0..31
    const float b2B = b_r2[qB & 1];

    // ---- init ----
    for (int idx = tid; idx < 2 * 1024; idx += BLK) ((_Float16*)hp2)[idx] = (_Float16)0.0f;
    for (int idx = tid; idx < MM * SS * 2; idx += BLK) {
        const int m = idx >> 10, i = idx & 1023;          // i = t*2 + o
        v_lds[(i >> 1) * 8 + m * 2 + (i & 1)] = v_seq[(size_t)(row0 + m) * (SS * 2) + i];
    }
    if (tid < 64) {   // packed residual-MLP weights
        wpk[tid][0] = W_r1[tid*4];   wpk[tid][1] = W_r1[tid*4+1];
        wpk[tid][2] = W_r1[tid*4+2]; wpk[tid][3] = W_r1[tid*4+3];
        wpk[tid][4] = b_r1[tid];
        wpk[tid][5] = W_r2[tid];     wpk[tid][6] = W_r2[64 + tid];
        wpk[tid][7] = 0.0f;
    }
    if (tid < 8)
        xc[0][tid] = x0[(size_t)(row0 + (tid >> 1)) * 2 + (tid & 1)];
    __syncthreads();

    float hold = 0.0f;   // h[quad][j] in fp32 — the only recurrent state
    f32x2 vv2 = *(const f32x2*)&v_lds[quad * 2];   // prefetched v[t] (t=0)
    // x-projection terms hoisted off the post-MFMA critical path
    float vxr = vv2[0]*wr0 + vv2[1]*wr1 + br;
    float vxz = vv2[0]*wz0 + vv2[1]*wz1 + bz;
    float vxn = vv2[0]*wn0 + vv2[1]*wn1 + bni;

    for (int t = 0; t < SS; ++t) {
        const int cur = t & 1, nxt = cur ^ 1;

        // ---------- recurrence: 12 MFMA as 6 independent 2-deep chains ----------
        f32x4 aL0 = {0,0,0,0}, aL1 = {0,0,0,0}, aL2 = {0,0,0,0};
        f32x4 aG0 = {0,0,0,0}, aG1 = {0,0,0,0}, aG2 = {0,0,0,0};
        const _Float16* hb = &hp2[cur][rbase];
        {
            f16x8 af0 = *(const f16x8*)&hb[0 * 256];
            f16x8 af1 = *(const f16x8*)&hb[1 * 256];
            f16x8 af2 = *(const f16x8*)&hb[2 * 256];
            f16x8 af3 = *(const f16x8*)&hb[3 * 256];
            aL0 = __builtin_amdgcn_mfma_f32_16x16x32_f16(af0, whi[0][0], aL0, 0, 0, 0);
            aL1 = __builtin_amdgcn_mfma_f32_16x16x32_f16(af0, whi[1][0], aL1, 0, 0, 0);
            aL2 = __builtin_amdgcn_mfma_f32_16x16x32_f16(af0, whi[2][0], aL2, 0, 0, 0);
            aG0 = __builtin_amdgcn_mfma_f32_16x16x32_f16(af2, whi[0][2], aG0, 0, 0, 0);
            aG1 = __builtin_amdgcn_mfma_f32_16x16x32_f16(af2, whi[1][2], aG1, 0, 0, 0);
            aG2 = __builtin_amdgcn_mfma_f32_16x16x32_f16(af2, whi[2][2], aG2, 0, 0, 0);
            aL0 = __builtin_amdgcn_mfma_f32_16x16x32_f16(af1, whi[0][1], aL0, 0, 0, 0);
            aL1 = __builtin_amdgcn_mfma_f32_16x16x32_f16(af1, whi[1][1], aL1, 0, 0, 0);
            aL2 = __builtin_amdgcn_mfma_f32_16x16x32_f16(af1, whi[2][1], aL2, 0, 0, 0);
            aG0 = __builtin_amdgcn_mfma_f32_16x16x32_f16(af3, whi[0][3], aG0, 0, 0, 0);
            aG1 = __builtin_amdgcn_mfma_f32_16x16x32_f16(af3, whi[1][3], aG1, 0, 0, 0);
            aG2 = __builtin_amdgcn_mfma_f32_16x16x32_f16(af3, whi[2][3], aG2, 0, 0, 0);
        }
        // combine K-halves; acc[0]=hi dot, acc[1]=(lo*2048) dot -> exact-h gh
        const float gh0 = fmaf(aL0[1] + aG0[1], LO_INV, aL0[0] + aG0[0]);
        const float gh1 = fmaf(aL1[1] + aG1[1], LO_INV, aL1[0] + aG1[0]);
        const float gh2 = fmaf(aL2[1] + aG2[1], LO_INV, aL2[0] + aG2[0]);

        const float r  = rcp_fast(1.0f + exp2_fast((gh0 + vxr) * (-L2E)));
        const float z  = rcp_fast(1.0f + exp2_fast((gh1 + vxz) * (-L2E)));
        const float na = vxn + r * (gh2 + bnh);
        const float n  = fmaf(2.0f, rcp_fast(1.0f + exp2_fast(na * (-2.0f * L2E))), -1.0f);
        hold = fmaf(z, hold - n, n);

        const _Float16 hh = (_Float16)hold;
        hp2[nxt][wbase]     = hh;
        hp2[nxt][wbase + 8] = (_Float16)((hold - (float)hh) * LO_SCALE);
        ring[((t & (RS-1)) * 4 + quad) * RStr + j] = hh;   // h_seq[t] for the epilogue

        // prefetch + precompute next step's x-projection (barrier shadow)
        vv2 = *(const f32x2*)&v_lds[((t + 1) & (SS - 1)) * 8 + quad * 2];
        vxr = vv2[0]*wr0 + vv2[1]*wr1 + br;
        vxz = vv2[0]*wz0 + vv2[1]*wz1 + bz;
        vxn = vv2[0]*wn0 + vv2[1]*wn1 + bni;

        __syncthreads();

        // ---------- batched epilogue every RS steps ----------
        if ((t & (RS - 1)) == (RS - 1)) {
            const int f  = t >> 5;       // flush index
            const int t0 = t - (RS - 1);

            // pass A: x_pred for the window (8-lane dot groups, 4 passes)
            if (tid < 8) xs[0][tid] = xc[f & 1][tid];
#pragma unroll
            for (int p = 0; p < 4; ++p) {
                const int tt = p * 8 + tt8;
                const f16x8 h0 = *(const f16x8*)&ring[(tt * 4 + mA) * RStr + l8 * 16];
                const f16x8 h1 = *(const f16x8*)&ring[(tt * 4 + mA) * RStr + l8 * 16 + 8];
                float acc = 0.0f;
#pragma unroll
                for (int i = 0; i < 8; ++i) {
                    acc += (float)h0[i] * woA[i];
                    acc += (float)h1[i] * woA[8 + i];
                }
                acc += __shfl_xor(acc, 1, 64);
                acc += __shfl_xor(acc, 2, 64);
                acc += __shfl_xor(acc, 4, 64);
                if (l8 == 0) xs[1 + tt][mA * 2 + oA] = acc + boA;
            }
            __syncthreads();

            // pass B: residual MLP + violations + stores; thread = (tB, mB, qB)
            // u = uu*4 + qB: the 4 qB lanes read banks {0,8,16,24} -> conflict-free
            {
                const float xp0 = xs[tB][mB*2], xp1 = xs[tB][mB*2+1];
                const f32x2 vt2 = *(const f32x2*)&v_lds[(t0 + tB) * 8 + mB * 2];
                float rss0 = 0.0f, rss1 = 0.0f;
#pragma unroll
                for (int uu = 0; uu < 16; ++uu) {
                    const int u = uu * 4 + qB;
                    const f32x4 wA = *(const f32x4*)&wpk[u][0];
                    const f32x4 wB = *(const f32x4*)&wpk[u][4];
                    const float hu = fmaxf(wB[0] + wA[0]*xp0 + wA[1]*xp1 + wA[2]*vt2[0] + wA[3]*vt2[1], 0.0f);
                    rss0 += hu * wB[1];
                    rss1 += hu * wB[2];
                }
                rss0 += __shfl_xor(rss0, 1, 64);
                rss1 += __shfl_xor(rss1, 1, 64);
                rss0 += __shfl_xor(rss0, 2, 64);
                rss1 += __shfl_xor(rss1, 2, 64);
                if (qB < 2) {
                    const int o = qB;
                    const float xpred = xs[tB + 1][mB*2 + o];
                    const float xpv   = xs[tB][mB*2 + o];
                    const float vv    = v_lds[(t0 + tB) * 8 + mB*2 + o];
                    const float resid = (o ? rss1 : rss0) + b2B;
                    const float viol  = xpred - (xpv + vv + resid);
                    const size_t base = (size_t)(row0 + mB) * (SS * 2) + (t0 + tB) * 2 + o;
                    out[base] = xpred;
                    out[(size_t)BB * SS * 2 + base] = viol;
                }
                if (tid < 8) xc[(f + 1) & 1][tid] = xs[RS][tid];   // carry to next window
            }
            __syncthreads();
        }
    }
}

extern "C" void kernel_launch(void* const* d_in, const int* in_sizes, int n_in,
                              void* d_out, int out_size, void* d_ws, size_t ws_size,
                              hipStream_t stream) {
    pig_kernel<<<dim3(NBLK), dim3(BLK), 0, stream>>>(
        (const float*)d_in[0],  (const float*)d_in[1],  (const float*)d_in[2],
        (const float*)d_in[3],  (const float*)d_in[4],  (const float*)d_in[5],
        (const float*)d_in[6],  (const float*)d_in[7],  (const float*)d_in[8],
        (const float*)d_in[9],  (const float*)d_in[10], (const float*)d_in[11],
        (float*)d_out);
}